// Round 3
// baseline (169.131 us; speedup 1.0000x reference)
//
#include <hip/hip_runtime.h>
#include <math.h>

#define N_NODES 50000
#define IN_CH 256
#define N_REL 5
#define N_EDGES 800000
#define N_GLOB 20000   // LAST_GLOBALS - LAST_SENSES
#define N_SENSE 25000
#define N_OUT 45000
#define MAX_MATCH 256  // E[matches]=16; 256 is astronomically safe
#define NBLK_LOGITS (N_OUT / 4)   // 11250, 4 rows per block
#define NBLK_GLOB (N_GLOB / 4)    // 5000 -> segment boundary block-aligned

// ---------------- workspace layout (floats from base) ----------------
// x1acc  : [0, 256)        atomic accumulator for pre-relu x1 (memset to 0)
// ip     : ints at float offset 256: ip[0]=match count, ip[1..5]=per-rel cnt,
//          ip[8..8+256)=src, ip[8+256..8+512)=type  (ip[0..7] memset to 0)
// pmax   : [1024, 1024+11250)
// psum   : [12274, 12274+11250)
// memset covers [0, 264) floats = 1056 bytes.

__device__ __forceinline__ void record_edge(const int* ei, const int* et,
                                            int* ip, int e) {
    int t = et[e];
    int p = atomicAdd(&ip[0], 1);
    if (p < MAX_MATCH) {
        ip[8 + p] = ei[e];               // src
        ip[8 + MAX_MATCH + p] = t;       // type
    }
    atomicAdd(&ip[1 + t], 1);
}

// collect edges with dst == 0 (int4-vectorized dst scan)
__global__ void k_scan(const int* __restrict__ ei,
                       const int* __restrict__ et,
                       int* __restrict__ ip) {
    int e4 = blockIdx.x * 256 + threadIdx.x;
    if (e4 * 4 >= N_EDGES) return;
    int4 d = ((const int4*)(ei + N_EDGES))[e4];
    int e = e4 * 4;
    if (d.x == 0) record_edge(ei, et, ip, e);
    if (d.y == 0) record_edge(ei, et, ip, e + 1);
    if (d.z == 0) record_edge(ei, et, ip, e + 2);
    if (d.w == 0) record_edge(ei, et, ip, e + 3);
}

// 6 blocks x 1024 thr. Blocks 0..4: u[b] = sum_j comp[r_j,b]/cnt_{r_j} * x[src_j],
// then x1acc += u[b] @ basis[b]  (4-way K-split).  Block 5: x1acc += x[0]@root + bias.
// W = einsum(comp, basis) is never materialized.
__global__ __launch_bounds__(1024) void k_x1(const float* __restrict__ x,
                                             const float* __restrict__ comp,
                                             const float* __restrict__ basis,
                                             const float* __restrict__ root,
                                             const float* __restrict__ bias,
                                             const int* __restrict__ ip,
                                             float* __restrict__ x1acc) {
    __shared__ float u[IN_CH];
    __shared__ float red[4][IN_CH];
    int tid = threadIdx.x;
    int f = tid & 255, c = tid >> 8;
    int b = blockIdx.x;
    const float* M;
    if (b < 5) {
        if (c == 0) {
            int m = ip[0]; if (m > MAX_MATCH) m = MAX_MATCH;
            float acc = 0.f;
            for (int j = 0; j < m; ++j) {
                int s = ip[8 + j];
                int t = ip[8 + MAX_MATCH + j];
                float scale = comp[t * N_REL + b] /
                              fmaxf((float)ip[1 + t], 1.0f);
                acc += scale * x[(size_t)s * IN_CH + f];
            }
            u[f] = acc;
        }
        M = basis + (size_t)b * IN_CH * IN_CH;
    } else {
        if (c == 0) u[f] = x[f];
        M = root;
    }
    __syncthreads();
    const float* Mr = M + c * 64 * IN_CH;
    float acc = 0.f;
#pragma unroll 8
    for (int d = 0; d < 64; ++d) acc += u[c * 64 + d] * Mr[d * IN_CH + f];
    red[c][f] = acc;
    __syncthreads();
    if (c == 0) {
        float a = red[0][f] + red[1][f] + red[2][f] + red[3][f];
        if (b == 5) a += bias[f];
        atomicAdd(&x1acc[f], a);
    }
}

// 4 rows per block (1 wave each); relu applied on x1acc read;
// fused per-block (max, sumexp) partials
__global__ void k_logits(const float* __restrict__ Wg,
                         const float* __restrict__ bg,
                         const float* __restrict__ Ws,
                         const float* __restrict__ bs,
                         const float* __restrict__ x1acc,
                         float* __restrict__ out,
                         float* __restrict__ pmax,
                         float* __restrict__ psum) {
    __shared__ float sx[IN_CH];
    __shared__ float sl[4];
    int tid = threadIdx.x;
    sx[tid] = fmaxf(x1acc[tid], 0.f);
    __syncthreads();
    int lane = tid & 63, w = tid >> 6;
    int row = blockIdx.x * 4 + w;          // N_OUT = 4*11250, no guard needed
    const float4* wr;
    float b;
    if (row < N_GLOB) {
        wr = (const float4*)(Wg + (size_t)row * IN_CH);
        b = bg[row];
    } else {
        int r2 = row - N_GLOB;
        wr = (const float4*)(Ws + (size_t)r2 * IN_CH);
        b = bs[r2];
    }
    float4 wv = wr[lane];
    float4 xv = ((const float4*)sx)[lane];
    float s = wv.x * xv.x + wv.y * xv.y + wv.z * xv.z + wv.w * xv.w;
#pragma unroll
    for (int off = 32; off > 0; off >>= 1) s += __shfl_down(s, off);
    if (lane == 0) { float l = s + b; out[row] = l; sl[w] = l; }
    __syncthreads();
    if (tid == 0) {
        float m4 = fmaxf(fmaxf(sl[0], sl[1]), fmaxf(sl[2], sl[3]));
        float s4 = expf(sl[0] - m4) + expf(sl[1] - m4) +
                   expf(sl[2] - m4) + expf(sl[3] - m4);
        pmax[blockIdx.x] = m4;
        psum[blockIdx.x] = s4;
    }
}

// fused stats+normalize: each of 176 blocks redundantly merges the (L2-hot)
// per-block partials for BOTH segments, then normalizes its 256 rows.
__global__ void k_statsfinal(const float* __restrict__ pmax,
                             const float* __restrict__ psum,
                             float* __restrict__ out) {
    __shared__ float rmg[256], rsg[256], rms[256], rss[256];
    int tid = threadIdx.x;
    float mg = -3.4e38f, sg = 0.f, ms = -3.4e38f, ss = 0.f;
    for (int i = tid; i < NBLK_LOGITS; i += 256) {
        float mi = pmax[i], si = psum[i];
        if (i < NBLK_GLOB) {
            float M = fmaxf(mg, mi);
            sg = sg * expf(mg - M) + si * expf(mi - M); mg = M;
        } else {
            float M = fmaxf(ms, mi);
            ss = ss * expf(ms - M) + si * expf(mi - M); ms = M;
        }
    }
    rmg[tid] = mg; rsg[tid] = sg; rms[tid] = ms; rss[tid] = ss;
    __syncthreads();
    for (int h = 128; h > 0; h >>= 1) {
        if (tid < h) {
            float m2 = rmg[tid + h], s2 = rsg[tid + h];
            float M = fmaxf(rmg[tid], m2);
            rsg[tid] = rsg[tid] * expf(rmg[tid] - M) + s2 * expf(m2 - M);
            rmg[tid] = M;
            m2 = rms[tid + h]; s2 = rss[tid + h];
            M = fmaxf(rms[tid], m2);
            rss[tid] = rss[tid] * expf(rms[tid] - M) + s2 * expf(m2 - M);
            rms[tid] = M;
        }
        __syncthreads();
    }
    float zg = rmg[0] + logf(rsg[0]);
    float zs = rms[0] + logf(rss[0]);
    int row = blockIdx.x * 256 + tid;
    if (row < N_OUT) out[row] -= (row < N_GLOB) ? zg : zs;
}

extern "C" void kernel_launch(void* const* d_in, const int* in_sizes, int n_in,
                              void* d_out, int out_size, void* d_ws, size_t ws_size,
                              hipStream_t stream) {
    const float* x     = (const float*)d_in[0];
    const int*   ei    = (const int*)  d_in[1];
    const int*   et    = (const int*)  d_in[2];
    const float* comp  = (const float*)d_in[3];
    const float* basis = (const float*)d_in[4];
    const float* root  = (const float*)d_in[5];
    const float* bias  = (const float*)d_in[6];
    const float* Wg    = (const float*)d_in[7];
    const float* bg    = (const float*)d_in[8];
    const float* Wsn   = (const float*)d_in[9];
    const float* bs    = (const float*)d_in[10];
    float* out = (float*)d_out;

    float* base  = (float*)d_ws;
    float* x1acc = base;                 // 256
    int*   ip    = (int*)(base + 256);   // 8 + 2*MAX_MATCH ints
    float* pmax  = base + 1024;          // 11250
    float* psum  = base + 12274;         // 11250

    hipMemsetAsync(d_ws, 0, 264 * sizeof(float), stream);  // x1acc + ip[0..7]
    k_scan      <<<(N_EDGES / 4 + 255) / 256, 256, 0, stream>>>(ei, et, ip);
    k_x1        <<<6, 1024, 0, stream>>>(x, comp, basis, root, bias, ip, x1acc);
    k_logits    <<<NBLK_LOGITS, 256, 0, stream>>>(Wg, bg, Wsn, bs, x1acc, out, pmax, psum);
    k_statsfinal<<<(N_OUT + 255) / 256, 256, 0, stream>>>(pmax, psum, out);
}